// Round 15
// baseline (449.559 us; speedup 1.0000x reference)
//
#include <hip/hip_runtime.h>
#include <hip/hip_bf16.h>

#define B_N   16384
#define D_N   17
#define H_N   256
#define E_N   64

typedef __attribute__((ext_vector_type(8))) short bf16x8;
typedef __attribute__((ext_vector_type(4))) float f32x4;

#define WAITL()  asm volatile("s_waitcnt lgkmcnt(0)" ::: "memory")
#define BAR()    __builtin_amdgcn_s_barrier()

static __device__ __forceinline__ short f2bf(float f){
  unsigned u = __builtin_bit_cast(unsigned, f);
  unsigned r = (u + 0x7fffu + ((u >> 16) & 1u)) >> 16;   // RNE
  return (short)(unsigned short)r;
}
static __device__ __forceinline__ float bf2f(short s){
  unsigned u = ((unsigned)(unsigned short)s) << 16;
  return __builtin_bit_cast(float, u);
}
static __device__ __forceinline__ float lrelu(float v){ return fmaxf(v, 0.01f * v); }

// ---------- prep: fp32 (G,R,C) -> bf16 (G,C,R) ----------
__global__ void transpose_convert(const float* __restrict__ in, short* __restrict__ outp,
                                  int R, int C){
  __shared__ float tile[32][33];
  int g = blockIdx.z;
  const float* inp = in + (size_t)g * R * C;
  short* op = outp + (size_t)g * R * C;
  int c0 = blockIdx.x * 32, r0 = blockIdx.y * 32;
  for (int i = threadIdx.y; i < 32; i += 8)
    tile[i][threadIdx.x] = inp[(size_t)(r0 + i) * C + c0 + threadIdx.x];
  __syncthreads();
  for (int i = threadIdx.y; i < 32; i += 8)
    op[(size_t)(c0 + i) * R + r0 + threadIdx.x] = f2bf(tile[threadIdx.x][i]);
}

// ---------- prep: stack+convert Wq|Wk|Wv -> bf16 [192][64] ----------
__global__ void convert_wqkv(const float* __restrict__ Wq, const float* __restrict__ Wk,
                             const float* __restrict__ Wv, short* __restrict__ outw){
  int i = blockIdx.x * 256 + threadIdx.x;        // 0..12287
  int g = i >> 12, r = i & 4095;
  const float* W = (g == 0) ? Wq : (g == 1 ? Wk : Wv);
  outw[i] = f2bf(W[r]);
}

// ---------- prep: wcomb[e] = sum_eo Wo[eo][e]*Wfc[eo]; wcomb[64] = bo.Wfc + bfc ----------
__global__ void wcomb_kernel(const float* __restrict__ Wo, const float* __restrict__ Wfc,
                             const float* __restrict__ bo, const float* __restrict__ bfc,
                             float* __restrict__ wcomb){
  int e = threadIdx.x;
  float acc = 0.f;
  for (int eo = 0; eo < 64; ++eo) acc += Wo[eo * 64 + e] * Wfc[eo];
  wcomb[e] = acc;
  if (e == 0){
    float bc = bfc[0];
    for (int eo = 0; eo < 64; ++eo) bc += bo[eo] * Wfc[eo];
    wcomb[64] = bc;
  }
}

// load 4 B-fragments (global -> regs): SGPR base + per-thread short offset +
// compile-time kk*32 shorts (imm-folds into the load).
static __device__ __forceinline__ void ldB(bf16x8* b, const short* base,
                                           const int* off, int kk){
  #pragma unroll
  for (int fc = 0; fc < 4; ++fc)
    b[fc] = *(const bf16x8*)(base + off[fc] + kk * 32);
}

// ---------- main subnet kernel ----------
// R14 diagnosis: the LDS data pipe was 100% saturated (48 ds_read_b128 + 16KB
// DMA per block-step ~700cyc x 2 blocks ~ wall). Fix: B never touches LDS —
// global -> register double-buffer (b0/b1: prefetch slice kk+2 right after
// slice kk is consumed; cross-layer prefetch at kk=6/7; first slices issued
// before phase 0). LDS carries only A. B is d-swizzled L2-resident. NO
// barriers inside K-loops (B not shared); 2 barriers per layer boundary for
// the in-place hbuf only. R3/R4 failed this shape for identified reasons:
// no reg prefetch + 64-VGPR cap (R4), 2 waves/SIMD lockstep (R3). Here:
// (256,3) = 170-reg cap (64 AGPR + ~75 VGPR fits), 32KB LDS -> 3 blocks/CU.
__global__ __launch_bounds__(256, 3) void subnet_kernel(
    const float* __restrict__ x, const float* __restrict__ W1, const float* __restrict__ b1v,
    const float* __restrict__ bm, const float* __restrict__ bf_,
    const float* __restrict__ bq, const float* __restrict__ bk, const float* __restrict__ bv,
    const short* __restrict__ WmT, const short* __restrict__ WfT, const short* __restrict__ Wqkv,
    short* __restrict__ qkv)
{
  __shared__ short hbuf[64 * 256];       // 32 KB activations (tokens overlay head)

  // XCD swizzle: 4352 = 8*544, d-major (per-XCD weight set L2-resident)
  int wg = blockIdx.x;
  int idx = (wg & 7) * 544 + (wg >> 3);
  const int d  = idx >> 8;
  const int m0 = (idx & 255) * 64;

  const int tid = threadIdx.x;
  const int lane = tid & 63, wave = tid >> 6;
  const int l15 = lane & 15, lhi = lane >> 4;

  const short* WtL0 = WmT + (size_t)(0 * D_N + d) * (H_N * H_N);
  const short* WtL1 = WmT + (size_t)(1 * D_N + d) * (H_N * H_N);
  const short* Wfd  = WfT + (size_t)d * (E_N * H_N);

  // per-thread B offsets (short units): middle n = wave*64+fc*16+l15; Wf n = fc*16+l15
  int off[4], offW[4];
  #pragma unroll
  for (int fc = 0; fc < 4; ++fc){
    off[fc]  = (wave * 64 + fc * 16 + l15) * 256 + lhi * 8;
    offW[fc] = (fc * 16 + l15) * 256 + lhi * 8;
  }

  // issue L0 slices 0,1 now — latency hides under phase 0
  bf16x8 bb0[4], bb1[4];
  ldB(bb0, WtL0, off, 0);
  ldB(bb1, WtL0, off, 1);

  // ---- phase 0: h0 = lrelu(x*W1+b1) -> swizzled LDS [m][k], packed b32 writes
  {
    const int kp = tid & 127;            // k-pair, k0 = 2*kp
    const int mh = tid >> 7;             // 0/1 -> m half
    const float w1a = W1[d * H_N + 2 * kp],  w1b = W1[d * H_N + 2 * kp + 1];
    const float c1a = b1v[d * H_N + 2 * kp], c1b = b1v[d * H_N + 2 * kp + 1];
    #pragma unroll
    for (int i = 0; i < 32; ++i){
      int m = mh * 32 + i;
      float xv = x[(size_t)(m0 + m) * D_N + d];
      unsigned lo = (unsigned short)f2bf(lrelu(xv * w1a + c1a));
      unsigned hi = (unsigned short)f2bf(lrelu(xv * w1b + c1b));
      int byte = m * 512 + ((((kp >> 2) ^ (m & 7))) << 4) + ((kp & 3) << 2);
      *(unsigned*)((char*)&hbuf[0] + byte) = lo | (hi << 16);
    }
  }
  WAITL();
  BAR();   // h0 visible to all waves

  // ---- 2 middle layers: (64x256)@(256x256); wave = 64-col slice; in-place;
  // B in registers, barrier-free K-loop.
  for (int L = 0; L < 2; ++L){
    const short* Wt = L ? WtL1 : WtL0;
    const float* bias = bm + (size_t)(L * D_N + d) * H_N;
    f32x4 acc[4][4];
    #pragma unroll
    for (int a = 0; a < 4; ++a)
      #pragma unroll
      for (int c = 0; c < 4; ++c) acc[a][c] = (f32x4){0.f, 0.f, 0.f, 0.f};

    #pragma unroll
    for (int kk = 0; kk < 8; ++kk){
      bf16x8* bc = (kk & 1) ? bb1 : bb0;    // compile-time after unroll
      #pragma unroll
      for (int fr = 0; fr < 4; ++fr){
        int row = fr * 16 + l15;
        int cch = kk * 4 + lhi;
        bf16x8 a = *(const bf16x8*)((const char*)&hbuf[0] + row * 512 + ((cch ^ (row & 7)) << 4));
        #pragma unroll
        for (int fc = 0; fc < 4; ++fc)
          acc[fr][fc] = __builtin_amdgcn_mfma_f32_16x16x32_bf16(a, bc[fc], acc[fr][fc], 0, 0, 0);
      }
      // refill the just-consumed buffer: slice kk+2 (or next matrix slice 0/1)
      if (kk < 6)       ldB(bc, Wt, off, kk + 2);
      else if (L == 0)  ldB(bc, WtL1, off, kk - 6);
      else              ldB(bc, Wfd, offW, kk - 6);
    }
    BAR();   // all waves done READING hbuf before in-place overwrite
    #pragma unroll
    for (int fr = 0; fr < 4; ++fr)
      #pragma unroll
      for (int fc = 0; fc < 4; ++fc)
        #pragma unroll
        for (int j = 0; j < 4; ++j){
          int row = fr * 16 + lhi * 4 + j;
          int col = wave * 64 + fc * 16 + l15;
          float v = lrelu(acc[fr][fc][j] + bias[col]);
          int byte = row * 512 + ((((col >> 3) ^ (row & 7))) << 4) + ((col & 7) << 1);
          *(short*)((char*)&hbuf[0] + byte) = f2bf(v);
        }
    WAITL();  // own epilogue ds_writes drained; visibility via next barrier
    BAR();
  }

  // ---- Wf layer: (64x256)@(256x64) + bf -> tokens overlay in hbuf [m][64]
  // Wave tile 16r x 64c (r0 = wave*16); B (Wf rows) in registers, barrier-free.
  {
    const int r0 = wave * 16;
    f32x4 acc[4];
    #pragma unroll
    for (int fc = 0; fc < 4; ++fc) acc[fc] = (f32x4){0.f, 0.f, 0.f, 0.f};
    #pragma unroll
    for (int kk = 0; kk < 8; ++kk){
      bf16x8* bc = (kk & 1) ? bb1 : bb0;
      int row = r0 + l15;
      int cch = kk * 4 + lhi;
      bf16x8 a = *(const bf16x8*)((const char*)&hbuf[0] + row * 512 + ((cch ^ (row & 7)) << 4));
      #pragma unroll
      for (int fc = 0; fc < 4; ++fc)
        acc[fc] = __builtin_amdgcn_mfma_f32_16x16x32_bf16(a, bc[fc], acc[fc], 0, 0, 0);
      if (kk < 6) ldB(bc, Wfd, offW, kk + 2);
    }
    BAR();   // all waves done reading hbuf before token overlay write
    #pragma unroll
    for (int fc = 0; fc < 4; ++fc)
      #pragma unroll
      for (int j = 0; j < 4; ++j){
        int row = r0 + lhi * 4 + j;
        int col = fc * 16 + l15;
        float v = acc[fc][j] + bf_[d * E_N + col];
        int byte = row * 128 + ((((col >> 3) ^ (row & 7))) << 4) + ((col & 7) << 1);
        *(short*)((char*)&hbuf[0] + byte) = f2bf(v);
      }
    WAITL();
    BAR();   // tokens visible to all waves
  }

  // ---- fused QKV: tokens(64x64) @ [Wq|Wk|Wv]^T (64x192); wave = 48-col slice
  // Wqkv is 24KB shared by ALL blocks -> L1/L2-hot; direct global loads fine.
  {
    f32x4 acc[4][3];
    #pragma unroll
    for (int fr = 0; fr < 4; ++fr)
      #pragma unroll
      for (int fc = 0; fc < 3; ++fc) acc[fr][fc] = (f32x4){0.f, 0.f, 0.f, 0.f};
    #pragma unroll
    for (int kk = 0; kk < 2; ++kk){
      bf16x8 af[4];
      #pragma unroll
      for (int fr = 0; fr < 4; ++fr){
        int row = fr * 16 + l15;
        int cch = kk * 4 + lhi;
        af[fr] = *(const bf16x8*)((const char*)&hbuf[0] + row * 128 + ((cch ^ (row & 7)) << 4));
      }
      bf16x8 bqkv[3];
      #pragma unroll
      for (int fc = 0; fc < 3; ++fc){
        int n = wave * 48 + fc * 16 + l15;
        bqkv[fc] = *(const bf16x8*)(Wqkv + (size_t)n * E_N + kk * 32 + lhi * 8);
      }
      #pragma unroll
      for (int fr = 0; fr < 4; ++fr)
        #pragma unroll
        for (int fc = 0; fc < 3; ++fc)
          acc[fr][fc] = __builtin_amdgcn_mfma_f32_16x16x32_bf16(af[fr], bqkv[fc], acc[fr][fc], 0, 0, 0);
    }
    #pragma unroll
    for (int fr = 0; fr < 4; ++fr)
      #pragma unroll
      for (int fc = 0; fc < 3; ++fc)
        #pragma unroll
        for (int j = 0; j < 4; ++j){
          int n = wave * 48 + fc * 16 + l15;
          int g = n >> 6, nl = n & 63;
          float bias = (g == 0) ? bq[nl] : (g == 1 ? bk[nl] : bv[nl]);
          int bg = m0 + fr * 16 + lhi * 4 + j;
          float v = acc[fr][fc][j] + bias;
          qkv[((size_t)bg * D_N + d) * 192 + n] = f2bf(v);
        }
  }
}

// ---------- attention + pool + folded head (R12 passing version, unchanged) ----------
__global__ __launch_bounds__(256, 2) void attn_kernel(
    const short* __restrict__ qkv, const float* __restrict__ wc, float* __restrict__ out)
{
  __shared__ short smem[4][17 * 192];     // per-wave sample tile, XOR-swizzled 16B chunks
  const int tid = threadIdx.x, lane = tid & 63, wave = tid >> 6;
  const int h = lane >> 4, iq = lane & 15;

  const int b = blockIdx.x * 4 + wave;
  const short* src = qkv + (size_t)b * (17 * 192);
  for (int g0 = lane; g0 < 408; g0 += 64){
    int i = g0 / 24, c = g0 % 24;
    bf16x8 v = *(const bf16x8*)(src + g0 * 8);
    *(bf16x8*)((char*)&smem[wave][0] + i * 384 + ((c ^ (i & 7)) << 4)) = v;
  }
  // same-wave LDS RAW is in-order; compiler inserts lgkmcnt waits before uses

  // pre-dot: vtilde_j = v_j . wcomb (head h slice). Lane holds j = iq;
  // j = 16 computed redundantly by every lane (lane-local, no shuffle).
  float vt = 0.f, vt16 = 0.f;
  #pragma unroll
  for (int u2 = 0; u2 < 2; ++u2){
    int cch = 16 + 2 * h + u2;
    bf16x8 vj  = *(const bf16x8*)((char*)&smem[wave][0] + iq * 384 + ((cch ^ (iq & 7)) << 4));
    bf16x8 v16 = *(const bf16x8*)((char*)&smem[wave][0] + 16 * 384 + (cch << 4));
    #pragma unroll
    for (int z = 0; z < 8; ++z){
      float w = wc[h * 16 + u2 * 8 + z];   // transient; L1-broadcast within head group
      vt   += bf2f(vj[z])  * w;
      vt16 += bf2f(v16[z]) * w;
    }
  }

  float part = 0.f;
  #pragma unroll 1
  for (int t = 0; t < 2; ++t){
    const int i = (t == 0) ? iq : 16;    // t=1: ALL lanes compute row 16 (uniform)
    float q[16];
    #pragma unroll
    for (int u2 = 0; u2 < 2; ++u2){
      int cch = 2 * h + u2;
      bf16x8 v = *(const bf16x8*)((char*)&smem[wave][0] + i * 384 + ((cch ^ (i & 7)) << 4));
      #pragma unroll
      for (int z = 0; z < 8; ++z) q[u2 * 8 + z] = bf2f(v[z]);
    }
    // fused softmax-PV: num = sum_j exp(s_j)*vtilde_j ; den = sum_j exp(s_j)
    float num = 0.f, den = 0.f;
    #pragma unroll 1                      // cap in-flight LDS loads / live range
    for (int j = 0; j < 16; ++j){
      float a2 = 0.f;
      #pragma unroll
      for (int u2 = 0; u2 < 2; ++u2){
        int cch = 8 + 2 * h + u2;
        bf16x8 v = *(const bf16x8*)((char*)&smem[wave][0] + j * 384 + ((cch ^ (j & 7)) << 4));
        #pragma unroll
        for (int z = 0; z < 8; ++z) a2 += q[u2 * 8 + z] * bf2f(v[z]);
      }
      float e = __expf(a2 * 0.25f);       // 1/sqrt(16); |s| ~ O(1), exp safe
      num += e * __shfl(vt, (lane & 48) + j);   // uniform: all 64 lanes active
      den += e;
    }
    {  // j = 16 (row swizzle term is 0 since 16&7 == 0)
      float a2 = 0.f;
      #pragma unroll
      for (int u2 = 0; u2 < 2; ++u2){
        int cch = 8 + 2 * h + u2;
        bf16x8 v = *(const bf16x8*)((char*)&smem[wave][0] + 16 * 384 + (cch << 4));
        #pragma unroll
        for (int z = 0; z < 8; ++z) a2 += q[u2 * 8 + z] * bf2f(v[z]);
      }
      float e = __expf(a2 * 0.25f);
      num += e * vt16;
      den += e;
    }
    float contrib = num / den;
    part += (t == 0 || iq == 0) ? contrib : 0.f;     // predicated, not branched
  }
  // out = lrelu( (1/17) * sum part + bcomb ), reduce over 64 lanes (17 i x 4 h)
  #pragma unroll
  for (int off = 1; off < 64; off <<= 1) part += __shfl_xor(part, off);
  if (lane == 0) out[b] = lrelu(part * (1.f / 17.f) + wc[64]);
}

extern "C" void kernel_launch(void* const* d_in, const int* in_sizes, int n_in,
                              void* d_out, int out_size, void* d_ws, size_t ws_size,
                              hipStream_t stream)
{
  const float* x   = (const float*)d_in[0];
  const float* W1  = (const float*)d_in[1];
  const float* b1  = (const float*)d_in[2];
  const float* Wm  = (const float*)d_in[3];
  const float* bm  = (const float*)d_in[4];
  const float* Wf  = (const float*)d_in[5];
  const float* bf_ = (const float*)d_in[6];
  const float* Wq  = (const float*)d_in[7];
  const float* bq  = (const float*)d_in[8];
  const float* Wk  = (const float*)d_in[9];
  const float* bk  = (const float*)d_in[10];
  const float* Wv  = (const float*)d_in[11];
  const float* bv  = (const float*)d_in[12];
  const float* Wo  = (const float*)d_in[13];
  const float* bo  = (const float*)d_in[14];
  const float* Wfc = (const float*)d_in[15];
  const float* bfc = (const float*)d_in[16];
  float* out = (float*)d_out;
  (void)in_sizes; (void)n_in; (void)out_size; (void)ws_size;

  char* ws = (char*)d_ws;
  size_t off = 0;
  auto alloc = [&](size_t bytes) -> char* {
    char* p = ws + off;
    off = (off + bytes + 255) & ~(size_t)255;
    return p;
  };
  short* qkvb  = (short*)alloc((size_t)B_N * D_N * 192 * 2);      // ~102 MB
  short* WmT   = (short*)alloc((size_t)2 * D_N * H_N * H_N * 2);  // 4.5 MB
  short* WfT   = (short*)alloc((size_t)D_N * E_N * H_N * 2);      // 0.56 MB
  short* Wqkvb = (short*)alloc((size_t)192 * E_N * 2);
  float* wcomb = (float*)alloc(65 * sizeof(float));

  transpose_convert<<<dim3(8, 8, 2 * D_N), dim3(32, 8), 0, stream>>>(Wm, WmT, 256, 256);
  transpose_convert<<<dim3(2, 8, D_N),     dim3(32, 8), 0, stream>>>(Wf, WfT, 256, 64);
  convert_wqkv<<<dim3(48), dim3(256), 0, stream>>>(Wq, Wk, Wv, Wqkvb);
  wcomb_kernel<<<dim3(1), dim3(64), 0, stream>>>(Wo, Wfc, bo, bfc, wcomb);

  subnet_kernel<<<dim3(256 * D_N), dim3(256), 0, stream>>>(
      x, W1, b1, bm, bf_, bq, bk, bv, WmT, WfT, Wqkvb, qkvb);

  attn_kernel<<<dim3(4096), dim3(256), 0, stream>>>(qkvb, wcomb, out);
}

// Round 16
// 357.381 us; speedup vs baseline: 1.2579x; 1.2579x over previous
//
#include <hip/hip_runtime.h>
#include <hip/hip_bf16.h>

#define B_N   16384
#define D_N   17
#define H_N   256
#define E_N   64

typedef __attribute__((ext_vector_type(8))) short bf16x8;
typedef __attribute__((ext_vector_type(4))) float f32x4;

#define WAITL()  asm volatile("s_waitcnt lgkmcnt(0)" ::: "memory")
#define BAR()    __builtin_amdgcn_s_barrier()

static __device__ __forceinline__ short f2bf(float f){
  unsigned u = __builtin_bit_cast(unsigned, f);
  unsigned r = (u + 0x7fffu + ((u >> 16) & 1u)) >> 16;   // RNE
  return (short)(unsigned short)r;
}
static __device__ __forceinline__ float bf2f(short s){
  unsigned u = ((unsigned)(unsigned short)s) << 16;
  return __builtin_bit_cast(float, u);
}
static __device__ __forceinline__ float lrelu(float v){ return fmaxf(v, 0.01f * v); }

static __device__ __forceinline__ f32x4 MF(bf16x8 a, bf16x8 b, f32x4 c){
  return __builtin_amdgcn_mfma_f32_16x16x32_bf16(a, b, c, 0, 0, 0);
}
// single B-fragment load: base + per-thread offset + compile-time k*32 (imm-folds)
static __device__ __forceinline__ bf16x8 LDB(const short* base, int off, int kk){
  return *(const bf16x8*)(base + off + kk * 32);
}
// one K-step of the 64x64-per-wave middle layer: A from LDS, B from 4 NAMED regs
template<int KK>
static __device__ __forceinline__ void step4(f32x4 (&acc)[4][4], const short* hb,
    int l15, int lhi, bf16x8 B0, bf16x8 B1, bf16x8 B2, bf16x8 B3){
  #pragma unroll
  for (int fr = 0; fr < 4; ++fr){
    int row = fr * 16 + l15;
    int cch = KK * 4 + lhi;
    bf16x8 a = *(const bf16x8*)((const char*)hb + row * 512 + ((cch ^ (row & 7)) << 4));
    acc[fr][0] = MF(a, B0, acc[fr][0]);
    acc[fr][1] = MF(a, B1, acc[fr][1]);
    acc[fr][2] = MF(a, B2, acc[fr][2]);
    acc[fr][3] = MF(a, B3, acc[fr][3]);
  }
}
// one K-step of the Wf layer (16 rows per wave, 64 cols)
template<int KK>
static __device__ __forceinline__ void stepWf(f32x4 (&acc)[4], const short* hb,
    int r0, int l15, int lhi, bf16x8 B0, bf16x8 B1, bf16x8 B2, bf16x8 B3){
  int row = r0 + l15;
  int cch = KK * 4 + lhi;
  bf16x8 a = *(const bf16x8*)((const char*)hb + row * 512 + ((cch ^ (row & 7)) << 4));
  acc[0] = MF(a, B0, acc[0]);
  acc[1] = MF(a, B1, acc[1]);
  acc[2] = MF(a, B2, acc[2]);
  acc[3] = MF(a, B3, acc[3]);
}

// ---------- prep: fp32 (G,R,C) -> bf16 (G,C,R) ----------
__global__ void transpose_convert(const float* __restrict__ in, short* __restrict__ outp,
                                  int R, int C){
  __shared__ float tile[32][33];
  int g = blockIdx.z;
  const float* inp = in + (size_t)g * R * C;
  short* op = outp + (size_t)g * R * C;
  int c0 = blockIdx.x * 32, r0 = blockIdx.y * 32;
  for (int i = threadIdx.y; i < 32; i += 8)
    tile[i][threadIdx.x] = inp[(size_t)(r0 + i) * C + c0 + threadIdx.x];
  __syncthreads();
  for (int i = threadIdx.y; i < 32; i += 8)
    op[(size_t)(c0 + i) * R + r0 + threadIdx.x] = f2bf(tile[threadIdx.x][i]);
}

// ---------- prep: stack+convert Wq|Wk|Wv -> bf16 [192][64] ----------
__global__ void convert_wqkv(const float* __restrict__ Wq, const float* __restrict__ Wk,
                             const float* __restrict__ Wv, short* __restrict__ outw){
  int i = blockIdx.x * 256 + threadIdx.x;        // 0..12287
  int g = i >> 12, r = i & 4095;
  const float* W = (g == 0) ? Wq : (g == 1 ? Wk : Wv);
  outw[i] = f2bf(W[r]);
}

// ---------- prep: wcomb[e] = sum_eo Wo[eo][e]*Wfc[eo]; wcomb[64] = bo.Wfc + bfc ----------
__global__ void wcomb_kernel(const float* __restrict__ Wo, const float* __restrict__ Wfc,
                             const float* __restrict__ bo, const float* __restrict__ bfc,
                             float* __restrict__ wcomb){
  int e = threadIdx.x;
  float acc = 0.f;
  for (int eo = 0; eo < 64; ++eo) acc += Wo[eo * 64 + e] * Wfc[eo];
  wcomb[e] = acc;
  if (e == 0){
    float bc = bfc[0];
    for (int eo = 0; eo < 64; ++eo) bc += bo[eo] * Wfc[eo];
    wcomb[64] = bc;
  }
}

// ---------- main subnet kernel ----------
// R14: LDS pipe saturated (A+B+DMA ~ 700cyc/step vs wall). R15: B-in-regs was
// right but bb0[4]/bb1[4] + runtime pointer select -> SROA failed -> scratch
// spill (FETCH 217/WRITE 387MB). This round: NO arrays/pointers for B — eight
// NAMED bf16x8 (e0..e3/o0..o3), template<KK> steps, compile-time everything.
// Per-step pipe: 4 ds_read (48cyc) vs 16 MFMA (78cyc) -> MFMA-dominant.
// Barrier-free K-loops (B private); 2 barriers per layer boundary (in-place
// hbuf). (256,3) = 170-reg unified cap; need ~64 AGPR + ~80 VGPR = ~145.
// 32KB LDS -> 3 blocks/CU, 3 free-running waves/SIMD.
__global__ __launch_bounds__(256, 3) void subnet_kernel(
    const float* __restrict__ x, const float* __restrict__ W1, const float* __restrict__ b1v,
    const float* __restrict__ bm, const float* __restrict__ bf_,
    const float* __restrict__ bq, const float* __restrict__ bk, const float* __restrict__ bv,
    const short* __restrict__ WmT, const short* __restrict__ WfT, const short* __restrict__ Wqkv,
    short* __restrict__ qkv)
{
  __shared__ short hbuf[64 * 256];       // 32 KB activations (tokens overlay head)

  // XCD swizzle: 4352 = 8*544, d-major (per-XCD weight set L2-resident)
  int wg = blockIdx.x;
  int idx = (wg & 7) * 544 + (wg >> 3);
  const int d  = idx >> 8;
  const int m0 = (idx & 255) * 64;

  const int tid = threadIdx.x;
  const int lane = tid & 63, wave = tid >> 6;
  const int l15 = lane & 15, lhi = lane >> 4;

  const short* WtL0 = WmT + (size_t)(0 * D_N + d) * (H_N * H_N);
  const short* WtL1 = WmT + (size_t)(1 * D_N + d) * (H_N * H_N);
  const short* Wfd  = WfT + (size_t)d * (E_N * H_N);

  // per-thread B offsets (short units), NAMED scalars (no arrays)
  const int off0 = (wave * 64 +  0 + l15) * 256 + lhi * 8;
  const int off1 = (wave * 64 + 16 + l15) * 256 + lhi * 8;
  const int off2 = (wave * 64 + 32 + l15) * 256 + lhi * 8;
  const int off3 = (wave * 64 + 48 + l15) * 256 + lhi * 8;
  const int ofW0 = ( 0 + l15) * 256 + lhi * 8;
  const int ofW1 = (16 + l15) * 256 + lhi * 8;
  const int ofW2 = (32 + l15) * 256 + lhi * 8;
  const int ofW3 = (48 + l15) * 256 + lhi * 8;

  // prologue: L0 slices 0,1 -> latency hides under phase 0
  bf16x8 e0 = LDB(WtL0, off0, 0), e1 = LDB(WtL0, off1, 0),
         e2 = LDB(WtL0, off2, 0), e3 = LDB(WtL0, off3, 0);
  bf16x8 o0 = LDB(WtL0, off0, 1), o1 = LDB(WtL0, off1, 1),
         o2 = LDB(WtL0, off2, 1), o3 = LDB(WtL0, off3, 1);

  // ---- phase 0: h0 = lrelu(x*W1+b1) -> swizzled LDS [m][k], packed b32 writes
  {
    const int kp = tid & 127;            // k-pair, k0 = 2*kp
    const int mh = tid >> 7;             // 0/1 -> m half
    const float w1a = W1[d * H_N + 2 * kp],  w1b = W1[d * H_N + 2 * kp + 1];
    const float c1a = b1v[d * H_N + 2 * kp], c1b = b1v[d * H_N + 2 * kp + 1];
    #pragma unroll
    for (int i = 0; i < 32; ++i){
      int m = mh * 32 + i;
      float xv = x[(size_t)(m0 + m) * D_N + d];
      unsigned lo = (unsigned short)f2bf(lrelu(xv * w1a + c1a));
      unsigned hi = (unsigned short)f2bf(lrelu(xv * w1b + c1b));
      int byte = m * 512 + ((((kp >> 2) ^ (m & 7))) << 4) + ((kp & 3) << 2);
      *(unsigned*)((char*)&hbuf[0] + byte) = lo | (hi << 16);
    }
  }
  WAITL();
  BAR();   // h0 visible to all waves

  // ---- 2 middle layers: (64x256)@(256x256); wave = 64-col slice; in-place;
  // B in named registers, barrier-free K-loop, even/odd double buffer.
  for (int L = 0; L < 2; ++L){
    const short* Wt = L ? WtL1 : WtL0;
    const float* bias = bm + (size_t)(L * D_N + d) * H_N;
    f32x4 acc[4][4];
    #pragma unroll
    for (int a = 0; a < 4; ++a)
      #pragma unroll
      for (int c = 0; c < 4; ++c) acc[a][c] = (f32x4){0.f, 0.f, 0.f, 0.f};

    step4<0>(acc, hbuf, l15, lhi, e0, e1, e2, e3);
    e0 = LDB(Wt, off0, 2); e1 = LDB(Wt, off1, 2); e2 = LDB(Wt, off2, 2); e3 = LDB(Wt, off3, 2);
    step4<1>(acc, hbuf, l15, lhi, o0, o1, o2, o3);
    o0 = LDB(Wt, off0, 3); o1 = LDB(Wt, off1, 3); o2 = LDB(Wt, off2, 3); o3 = LDB(Wt, off3, 3);
    step4<2>(acc, hbuf, l15, lhi, e0, e1, e2, e3);
    e0 = LDB(Wt, off0, 4); e1 = LDB(Wt, off1, 4); e2 = LDB(Wt, off2, 4); e3 = LDB(Wt, off3, 4);
    step4<3>(acc, hbuf, l15, lhi, o0, o1, o2, o3);
    o0 = LDB(Wt, off0, 5); o1 = LDB(Wt, off1, 5); o2 = LDB(Wt, off2, 5); o3 = LDB(Wt, off3, 5);
    step4<4>(acc, hbuf, l15, lhi, e0, e1, e2, e3);
    e0 = LDB(Wt, off0, 6); e1 = LDB(Wt, off1, 6); e2 = LDB(Wt, off2, 6); e3 = LDB(Wt, off3, 6);
    step4<5>(acc, hbuf, l15, lhi, o0, o1, o2, o3);
    o0 = LDB(Wt, off0, 7); o1 = LDB(Wt, off1, 7); o2 = LDB(Wt, off2, 7); o3 = LDB(Wt, off3, 7);
    step4<6>(acc, hbuf, l15, lhi, e0, e1, e2, e3);
    if (L == 0){ e0 = LDB(WtL1, off0, 0); e1 = LDB(WtL1, off1, 0); e2 = LDB(WtL1, off2, 0); e3 = LDB(WtL1, off3, 0); }
    else       { e0 = LDB(Wfd, ofW0, 0); e1 = LDB(Wfd, ofW1, 0); e2 = LDB(Wfd, ofW2, 0); e3 = LDB(Wfd, ofW3, 0); }
    step4<7>(acc, hbuf, l15, lhi, o0, o1, o2, o3);
    if (L == 0){ o0 = LDB(WtL1, off0, 1); o1 = LDB(WtL1, off1, 1); o2 = LDB(WtL1, off2, 1); o3 = LDB(WtL1, off3, 1); }
    else       { o0 = LDB(Wfd, ofW0, 1); o1 = LDB(Wfd, ofW1, 1); o2 = LDB(Wfd, ofW2, 1); o3 = LDB(Wfd, ofW3, 1); }

    BAR();   // all waves done READING hbuf before in-place overwrite
    #pragma unroll
    for (int fr = 0; fr < 4; ++fr)
      #pragma unroll
      for (int fc = 0; fc < 4; ++fc)
        #pragma unroll
        for (int j = 0; j < 4; ++j){
          int row = fr * 16 + lhi * 4 + j;
          int col = wave * 64 + fc * 16 + l15;
          float v = lrelu(acc[fr][fc][j] + bias[col]);
          int byte = row * 512 + ((((col >> 3) ^ (row & 7))) << 4) + ((col & 7) << 1);
          *(short*)((char*)&hbuf[0] + byte) = f2bf(v);
        }
    WAITL();  // own epilogue ds_writes drained
    BAR();    // visible to all
  }

  // ---- Wf layer: (64x256)@(256x64) + bf -> tokens overlay in hbuf [m][64]
  // Wave tile 16r x 64c (r0 = wave*16); B in named regs, barrier-free.
  {
    const int r0w = wave * 16;
    f32x4 aw[4];
    #pragma unroll
    for (int fc = 0; fc < 4; ++fc) aw[fc] = (f32x4){0.f, 0.f, 0.f, 0.f};

    stepWf<0>(aw, hbuf, r0w, l15, lhi, e0, e1, e2, e3);
    e0 = LDB(Wfd, ofW0, 2); e1 = LDB(Wfd, ofW1, 2); e2 = LDB(Wfd, ofW2, 2); e3 = LDB(Wfd, ofW3, 2);
    stepWf<1>(aw, hbuf, r0w, l15, lhi, o0, o1, o2, o3);
    o0 = LDB(Wfd, ofW0, 3); o1 = LDB(Wfd, ofW1, 3); o2 = LDB(Wfd, ofW2, 3); o3 = LDB(Wfd, ofW3, 3);
    stepWf<2>(aw, hbuf, r0w, l15, lhi, e0, e1, e2, e3);
    e0 = LDB(Wfd, ofW0, 4); e1 = LDB(Wfd, ofW1, 4); e2 = LDB(Wfd, ofW2, 4); e3 = LDB(Wfd, ofW3, 4);
    stepWf<3>(aw, hbuf, r0w, l15, lhi, o0, o1, o2, o3);
    o0 = LDB(Wfd, ofW0, 5); o1 = LDB(Wfd, ofW1, 5); o2 = LDB(Wfd, ofW2, 5); o3 = LDB(Wfd, ofW3, 5);
    stepWf<4>(aw, hbuf, r0w, l15, lhi, e0, e1, e2, e3);
    e0 = LDB(Wfd, ofW0, 6); e1 = LDB(Wfd, ofW1, 6); e2 = LDB(Wfd, ofW2, 6); e3 = LDB(Wfd, ofW3, 6);
    stepWf<5>(aw, hbuf, r0w, l15, lhi, o0, o1, o2, o3);
    o0 = LDB(Wfd, ofW0, 7); o1 = LDB(Wfd, ofW1, 7); o2 = LDB(Wfd, ofW2, 7); o3 = LDB(Wfd, ofW3, 7);
    stepWf<6>(aw, hbuf, r0w, l15, lhi, e0, e1, e2, e3);
    stepWf<7>(aw, hbuf, r0w, l15, lhi, o0, o1, o2, o3);

    BAR();   // all waves done reading hbuf before token overlay write
    #pragma unroll
    for (int fc = 0; fc < 4; ++fc)
      #pragma unroll
      for (int j = 0; j < 4; ++j){
        int row = r0w + lhi * 4 + j;
        int col = fc * 16 + l15;
        float v = aw[fc][j] + bf_[d * E_N + col];
        int byte = row * 128 + ((((col >> 3) ^ (row & 7))) << 4) + ((col & 7) << 1);
        *(short*)((char*)&hbuf[0] + byte) = f2bf(v);
      }
    WAITL();
    BAR();   // tokens visible to all waves
  }

  // ---- fused QKV: tokens(64x64) @ [Wq|Wk|Wv]^T (64x192); wave = 48-col slice
  // Wqkv is 24KB shared by ALL blocks -> L1/L2-hot; direct global loads fine.
  {
    f32x4 acc[4][3];
    #pragma unroll
    for (int fr = 0; fr < 4; ++fr)
      #pragma unroll
      for (int fc = 0; fc < 3; ++fc) acc[fr][fc] = (f32x4){0.f, 0.f, 0.f, 0.f};
    #pragma unroll
    for (int kk = 0; kk < 2; ++kk){
      bf16x8 af[4];
      #pragma unroll
      for (int fr = 0; fr < 4; ++fr){
        int row = fr * 16 + l15;
        int cch = kk * 4 + lhi;
        af[fr] = *(const bf16x8*)((const char*)&hbuf[0] + row * 128 + ((cch ^ (row & 7)) << 4));
      }
      bf16x8 bqkv[3];
      #pragma unroll
      for (int fc = 0; fc < 3; ++fc){
        int n = wave * 48 + fc * 16 + l15;
        bqkv[fc] = *(const bf16x8*)(Wqkv + (size_t)n * E_N + kk * 32 + lhi * 8);
      }
      #pragma unroll
      for (int fr = 0; fr < 4; ++fr)
        #pragma unroll
        for (int fc = 0; fc < 3; ++fc)
          acc[fr][fc] = __builtin_amdgcn_mfma_f32_16x16x32_bf16(af[fr], bqkv[fc], acc[fr][fc], 0, 0, 0);
    }
    #pragma unroll
    for (int fr = 0; fr < 4; ++fr)
      #pragma unroll
      for (int fc = 0; fc < 3; ++fc)
        #pragma unroll
        for (int j = 0; j < 4; ++j){
          int n = wave * 48 + fc * 16 + l15;
          int g = n >> 6, nl = n & 63;
          float bias = (g == 0) ? bq[nl] : (g == 1 ? bk[nl] : bv[nl]);
          int bg = m0 + fr * 16 + lhi * 4 + j;
          float v = acc[fr][fc][j] + bias;
          qkv[((size_t)bg * D_N + d) * 192 + n] = f2bf(v);
        }
  }
}

// ---------- attention + pool + folded head (R12 passing version, unchanged) ----------
__global__ __launch_bounds__(256, 2) void attn_kernel(
    const short* __restrict__ qkv, const float* __restrict__ wc, float* __restrict__ out)
{
  __shared__ short smem[4][17 * 192];     // per-wave sample tile, XOR-swizzled 16B chunks
  const int tid = threadIdx.x, lane = tid & 63, wave = tid >> 6;
  const int h = lane >> 4, iq = lane & 15;

  const int b = blockIdx.x * 4 + wave;
  const short* src = qkv + (size_t)b * (17 * 192);
  for (int g0 = lane; g0 < 408; g0 += 64){
    int i = g0 / 24, c = g0 % 24;
    bf16x8 v = *(const bf16x8*)(src + g0 * 8);
    *(bf16x8*)((char*)&smem[wave][0] + i * 384 + ((c ^ (i & 7)) << 4)) = v;
  }
  // same-wave LDS RAW is in-order; compiler inserts lgkmcnt waits before uses

  // pre-dot: vtilde_j = v_j . wcomb (head h slice). Lane holds j = iq;
  // j = 16 computed redundantly by every lane (lane-local, no shuffle).
  float vt = 0.f, vt16 = 0.f;
  #pragma unroll
  for (int u2 = 0; u2 < 2; ++u2){
    int cch = 16 + 2 * h + u2;
    bf16x8 vj  = *(const bf16x8*)((char*)&smem[wave][0] + iq * 384 + ((cch ^ (iq & 7)) << 4));
    bf16x8 v16 = *(const bf16x8*)((char*)&smem[wave][0] + 16 * 384 + (cch << 4));
    #pragma unroll
    for (int z = 0; z < 8; ++z){
      float w = wc[h * 16 + u2 * 8 + z];   // transient; L1-broadcast within head group
      vt   += bf2f(vj[z])  * w;
      vt16 += bf2f(v16[z]) * w;
    }
  }

  float part = 0.f;
  #pragma unroll 1
  for (int t = 0; t < 2; ++t){
    const int i = (t == 0) ? iq : 16;    // t=1: ALL lanes compute row 16 (uniform)
    float q[16];
    #pragma unroll
    for (int u2 = 0; u2 < 2; ++u2){
      int cch = 2 * h + u2;
      bf16x8 v = *(const bf16x8*)((char*)&smem[wave][0] + i * 384 + ((cch ^ (i & 7)) << 4));
      #pragma unroll
      for (int z = 0; z < 8; ++z) q[u2 * 8 + z] = bf2f(v[z]);
    }
    // fused softmax-PV: num = sum_j exp(s_j)*vtilde_j ; den = sum_j exp(s_j)
    float num = 0.f, den = 0.f;
    #pragma unroll 1                      // cap in-flight LDS loads / live range
    for (int j = 0; j < 16; ++j){
      float a2 = 0.f;
      #pragma unroll
      for (int u2 = 0; u2 < 2; ++u2){
        int cch = 8 + 2 * h + u2;
        bf16x8 v = *(const bf16x8*)((char*)&smem[wave][0] + j * 384 + ((cch ^ (j & 7)) << 4));
        #pragma unroll
        for (int z = 0; z < 8; ++z) a2 += q[u2 * 8 + z] * bf2f(v[z]);
      }
      float e = __expf(a2 * 0.25f);       // 1/sqrt(16); |s| ~ O(1), exp safe
      num += e * __shfl(vt, (lane & 48) + j);   // uniform: all 64 lanes active
      den += e;
    }
    {  // j = 16 (row swizzle term is 0 since 16&7 == 0)
      float a2 = 0.f;
      #pragma unroll
      for (int u2 = 0; u2 < 2; ++u2){
        int cch = 8 + 2 * h + u2;
        bf16x8 v = *(const bf16x8*)((char*)&smem[wave][0] + 16 * 384 + (cch << 4));
        #pragma unroll
        for (int z = 0; z < 8; ++z) a2 += q[u2 * 8 + z] * bf2f(v[z]);
      }
      float e = __expf(a2 * 0.25f);
      num += e * vt16;
      den += e;
    }
    float contrib = num / den;
    part += (t == 0 || iq == 0) ? contrib : 0.f;     // predicated, not branched
  }
  // out = lrelu( (1/17) * sum part + bcomb ), reduce over 64 lanes (17 i x 4 h)
  #pragma unroll
  for (int off = 1; off < 64; off <<= 1) part += __shfl_xor(part, off);
  if (lane == 0) out[b] = lrelu(part * (1.f / 17.f) + wc[64]);
}

extern "C" void kernel_launch(void* const* d_in, const int* in_sizes, int n_in,
                              void* d_out, int out_size, void* d_ws, size_t ws_size,
                              hipStream_t stream)
{
  const float* x   = (const float*)d_in[0];
  const float* W1  = (const float*)d_in[1];
  const float* b1  = (const float*)d_in[2];
  const float* Wm  = (const float*)d_in[3];
  const float* bm  = (const float*)d_in[4];
  const float* Wf  = (const float*)d_in[5];
  const float* bf_ = (const float*)d_in[6];
  const float* Wq  = (const float*)d_in[7];
  const float* bq  = (const float*)d_in[8];
  const float* Wk  = (const float*)d_in[9];
  const float* bk  = (const float*)d_in[10];
  const float* Wv  = (const float*)d_in[11];
  const float* bv  = (const float*)d_in[12];
  const float* Wo  = (const float*)d_in[13];
  const float* bo  = (const float*)d_in[14];
  const float* Wfc = (const float*)d_in[15];
  const float* bfc = (const float*)d_in[16];
  float* out = (float*)d_out;
  (void)in_sizes; (void)n_in; (void)out_size; (void)ws_size;

  char* ws = (char*)d_ws;
  size_t off = 0;
  auto alloc = [&](size_t bytes) -> char* {
    char* p = ws + off;
    off = (off + bytes + 255) & ~(size_t)255;
    return p;
  };
  short* qkvb  = (short*)alloc((size_t)B_N * D_N * 192 * 2);      // ~102 MB
  short* WmT   = (short*)alloc((size_t)2 * D_N * H_N * H_N * 2);  // 4.5 MB
  short* WfT   = (short*)alloc((size_t)D_N * E_N * H_N * 2);      // 0.56 MB
  short* Wqkvb = (short*)alloc((size_t)192 * E_N * 2);
  float* wcomb = (float*)alloc(65 * sizeof(float));

  transpose_convert<<<dim3(8, 8, 2 * D_N), dim3(32, 8), 0, stream>>>(Wm, WmT, 256, 256);
  transpose_convert<<<dim3(2, 8, D_N),     dim3(32, 8), 0, stream>>>(Wf, WfT, 256, 64);
  convert_wqkv<<<dim3(48), dim3(256), 0, stream>>>(Wq, Wk, Wv, Wqkvb);
  wcomb_kernel<<<dim3(1), dim3(64), 0, stream>>>(Wo, Wfc, bo, bfc, wcomb);

  subnet_kernel<<<dim3(256 * D_N), dim3(256), 0, stream>>>(
      x, W1, b1, bm, bf_, bq, bk, bv, WmT, WfT, Wqkvb, qkvb);

  attn_kernel<<<dim3(4096), dim3(256), 0, stream>>>(qkvb, wcomb, out);
}

// Round 17
// 295.606 us; speedup vs baseline: 1.5208x; 1.2090x over previous
//
#include <hip/hip_runtime.h>
#include <hip/hip_bf16.h>

#define B_N   16384
#define D_N   17
#define H_N   256
#define E_N   64

typedef __attribute__((ext_vector_type(8))) short bf16x8;
typedef __attribute__((ext_vector_type(4))) float f32x4;

#define WAITL()  asm volatile("s_waitcnt lgkmcnt(0)" ::: "memory")
#define BAR()    __builtin_amdgcn_s_barrier()

static __device__ __forceinline__ short f2bf(float f){
  unsigned u = __builtin_bit_cast(unsigned, f);
  unsigned r = (u + 0x7fffu + ((u >> 16) & 1u)) >> 16;   // RNE
  return (short)(unsigned short)r;
}
static __device__ __forceinline__ float bf2f(short s){
  unsigned u = ((unsigned)(unsigned short)s) << 16;
  return __builtin_bit_cast(float, u);
}
static __device__ __forceinline__ float lrelu(float v){ return fmaxf(v, 0.01f * v); }

static __device__ __forceinline__ f32x4 MF(bf16x8 a, bf16x8 b, f32x4 c){
  return __builtin_amdgcn_mfma_f32_16x16x32_bf16(a, b, c, 0, 0, 0);
}
// single B-fragment load: base + per-thread offset + compile-time k*32 (imm-folds)
static __device__ __forceinline__ bf16x8 LDB(const short* base, int off, int kk){
  return *(const bf16x8*)(base + off + kk * 32);
}
// one K-step of the 64x64-per-wave middle layer: A from LDS, B from 4 NAMED regs
template<int KK>
static __device__ __forceinline__ void step4(f32x4 (&acc)[4][4], const short* hb,
    int l15, int lhi, bf16x8 B0, bf16x8 B1, bf16x8 B2, bf16x8 B3){
  #pragma unroll
  for (int fr = 0; fr < 4; ++fr){
    int row = fr * 16 + l15;
    int cch = KK * 4 + lhi;
    bf16x8 a = *(const bf16x8*)((const char*)hb + row * 512 + ((cch ^ (row & 7)) << 4));
    acc[fr][0] = MF(a, B0, acc[fr][0]);
    acc[fr][1] = MF(a, B1, acc[fr][1]);
    acc[fr][2] = MF(a, B2, acc[fr][2]);
    acc[fr][3] = MF(a, B3, acc[fr][3]);
  }
}
// one K-step of the Wf layer (16 rows per wave, 64 cols)
template<int KK>
static __device__ __forceinline__ void stepWf(f32x4 (&acc)[4], const short* hb,
    int r0, int l15, int lhi, bf16x8 B0, bf16x8 B1, bf16x8 B2, bf16x8 B3){
  int row = r0 + l15;
  int cch = KK * 4 + lhi;
  bf16x8 a = *(const bf16x8*)((const char*)hb + row * 512 + ((cch ^ (row & 7)) << 4));
  acc[0] = MF(a, B0, acc[0]);
  acc[1] = MF(a, B1, acc[1]);
  acc[2] = MF(a, B2, acc[2]);
  acc[3] = MF(a, B3, acc[3]);
}

// ---------- prep: fp32 (G,R,C) -> bf16 (G,C,R) ----------
__global__ void transpose_convert(const float* __restrict__ in, short* __restrict__ outp,
                                  int R, int C){
  __shared__ float tile[32][33];
  int g = blockIdx.z;
  const float* inp = in + (size_t)g * R * C;
  short* op = outp + (size_t)g * R * C;
  int c0 = blockIdx.x * 32, r0 = blockIdx.y * 32;
  for (int i = threadIdx.y; i < 32; i += 8)
    tile[i][threadIdx.x] = inp[(size_t)(r0 + i) * C + c0 + threadIdx.x];
  __syncthreads();
  for (int i = threadIdx.y; i < 32; i += 8)
    op[(size_t)(c0 + i) * R + r0 + threadIdx.x] = f2bf(tile[threadIdx.x][i]);
}

// ---------- prep: stack+convert Wq|Wk|Wv -> bf16 [192][64] ----------
__global__ void convert_wqkv(const float* __restrict__ Wq, const float* __restrict__ Wk,
                             const float* __restrict__ Wv, short* __restrict__ outw){
  int i = blockIdx.x * 256 + threadIdx.x;        // 0..12287
  int g = i >> 12, r = i & 4095;
  const float* W = (g == 0) ? Wq : (g == 1 ? Wk : Wv);
  outw[i] = f2bf(W[r]);
}

// ---------- prep: wcomb[e] = sum_eo Wo[eo][e]*Wfc[eo]; wcomb[64] = bo.Wfc + bfc ----------
__global__ void wcomb_kernel(const float* __restrict__ Wo, const float* __restrict__ Wfc,
                             const float* __restrict__ bo, const float* __restrict__ bfc,
                             float* __restrict__ wcomb){
  int e = threadIdx.x;
  float acc = 0.f;
  for (int eo = 0; eo < 64; ++eo) acc += Wo[eo * 64 + e] * Wfc[eo];
  wcomb[e] = acc;
  if (e == 0){
    float bc = bfc[0];
    for (int eo = 0; eo < 64; ++eo) bc += bo[eo] * Wfc[eo];
    wcomb[64] = bc;
  }
}

// ---------- main subnet kernel ----------
// R16: structure right, but the (256,3) bound (170-unified cap) forced the
// allocator to spill the B buffers (WRITE +152MB at VGPR 84). Session rule:
// EVERY forced-occupancy bound spilled (R2/R4/R16). This round: (256,2)
// (256-unified cap, never spilled) and let the allocator take ~150-170 —
// hardware then gives 3 waves/SIMD naturally. Barrier-free K-loops, B in
// named regs (e0..e3/o0..o3), template<KK> steps, A-only LDS (32KB -> 3+
// blocks/CU co-resident).
__global__ __launch_bounds__(256, 2) void subnet_kernel(
    const float* __restrict__ x, const float* __restrict__ W1, const float* __restrict__ b1v,
    const float* __restrict__ bm, const float* __restrict__ bf_,
    const float* __restrict__ bq, const float* __restrict__ bk, const float* __restrict__ bv,
    const short* __restrict__ WmT, const short* __restrict__ WfT, const short* __restrict__ Wqkv,
    short* __restrict__ qkv)
{
  __shared__ short hbuf[64 * 256];       // 32 KB activations (tokens overlay head)

  // XCD swizzle: 4352 = 8*544, d-major (per-XCD weight set L2-resident)
  int wg = blockIdx.x;
  int idx = (wg & 7) * 544 + (wg >> 3);
  const int d  = idx >> 8;
  const int m0 = (idx & 255) * 64;

  const int tid = threadIdx.x;
  const int lane = tid & 63, wave = tid >> 6;
  const int l15 = lane & 15, lhi = lane >> 4;

  const short* WtL0 = WmT + (size_t)(0 * D_N + d) * (H_N * H_N);
  const short* WtL1 = WmT + (size_t)(1 * D_N + d) * (H_N * H_N);
  const short* Wfd  = WfT + (size_t)d * (E_N * H_N);

  // per-thread B offsets (short units), NAMED scalars (no arrays)
  const int off0 = (wave * 64 +  0 + l15) * 256 + lhi * 8;
  const int off1 = (wave * 64 + 16 + l15) * 256 + lhi * 8;
  const int off2 = (wave * 64 + 32 + l15) * 256 + lhi * 8;
  const int off3 = (wave * 64 + 48 + l15) * 256 + lhi * 8;
  const int ofW0 = ( 0 + l15) * 256 + lhi * 8;
  const int ofW1 = (16 + l15) * 256 + lhi * 8;
  const int ofW2 = (32 + l15) * 256 + lhi * 8;
  const int ofW3 = (48 + l15) * 256 + lhi * 8;

  // prologue: L0 slices 0,1 -> latency hides under phase 0
  bf16x8 e0 = LDB(WtL0, off0, 0), e1 = LDB(WtL0, off1, 0),
         e2 = LDB(WtL0, off2, 0), e3 = LDB(WtL0, off3, 0);
  bf16x8 o0 = LDB(WtL0, off0, 1), o1 = LDB(WtL0, off1, 1),
         o2 = LDB(WtL0, off2, 1), o3 = LDB(WtL0, off3, 1);

  // ---- phase 0: h0 = lrelu(x*W1+b1) -> swizzled LDS [m][k], packed b32 writes
  {
    const int kp = tid & 127;            // k-pair, k0 = 2*kp
    const int mh = tid >> 7;             // 0/1 -> m half
    const float w1a = W1[d * H_N + 2 * kp],  w1b = W1[d * H_N + 2 * kp + 1];
    const float c1a = b1v[d * H_N + 2 * kp], c1b = b1v[d * H_N + 2 * kp + 1];
    #pragma unroll
    for (int i = 0; i < 32; ++i){
      int m = mh * 32 + i;
      float xv = x[(size_t)(m0 + m) * D_N + d];
      unsigned lo = (unsigned short)f2bf(lrelu(xv * w1a + c1a));
      unsigned hi = (unsigned short)f2bf(lrelu(xv * w1b + c1b));
      int byte = m * 512 + ((((kp >> 2) ^ (m & 7))) << 4) + ((kp & 3) << 2);
      *(unsigned*)((char*)&hbuf[0] + byte) = lo | (hi << 16);
    }
  }
  WAITL();
  BAR();   // h0 visible to all waves

  // ---- 2 middle layers: (64x256)@(256x256); wave = 64-col slice; in-place;
  // B in named registers, barrier-free K-loop, even/odd double buffer.
  for (int L = 0; L < 2; ++L){
    const short* Wt = L ? WtL1 : WtL0;
    const float* bias = bm + (size_t)(L * D_N + d) * H_N;
    f32x4 acc[4][4];
    #pragma unroll
    for (int a = 0; a < 4; ++a)
      #pragma unroll
      for (int c = 0; c < 4; ++c) acc[a][c] = (f32x4){0.f, 0.f, 0.f, 0.f};

    step4<0>(acc, hbuf, l15, lhi, e0, e1, e2, e3);
    e0 = LDB(Wt, off0, 2); e1 = LDB(Wt, off1, 2); e2 = LDB(Wt, off2, 2); e3 = LDB(Wt, off3, 2);
    step4<1>(acc, hbuf, l15, lhi, o0, o1, o2, o3);
    o0 = LDB(Wt, off0, 3); o1 = LDB(Wt, off1, 3); o2 = LDB(Wt, off2, 3); o3 = LDB(Wt, off3, 3);
    step4<2>(acc, hbuf, l15, lhi, e0, e1, e2, e3);
    e0 = LDB(Wt, off0, 4); e1 = LDB(Wt, off1, 4); e2 = LDB(Wt, off2, 4); e3 = LDB(Wt, off3, 4);
    step4<3>(acc, hbuf, l15, lhi, o0, o1, o2, o3);
    o0 = LDB(Wt, off0, 5); o1 = LDB(Wt, off1, 5); o2 = LDB(Wt, off2, 5); o3 = LDB(Wt, off3, 5);
    step4<4>(acc, hbuf, l15, lhi, e0, e1, e2, e3);
    e0 = LDB(Wt, off0, 6); e1 = LDB(Wt, off1, 6); e2 = LDB(Wt, off2, 6); e3 = LDB(Wt, off3, 6);
    step4<5>(acc, hbuf, l15, lhi, o0, o1, o2, o3);
    o0 = LDB(Wt, off0, 7); o1 = LDB(Wt, off1, 7); o2 = LDB(Wt, off2, 7); o3 = LDB(Wt, off3, 7);
    step4<6>(acc, hbuf, l15, lhi, e0, e1, e2, e3);
    if (L == 0){ e0 = LDB(WtL1, off0, 0); e1 = LDB(WtL1, off1, 0); e2 = LDB(WtL1, off2, 0); e3 = LDB(WtL1, off3, 0); }
    else       { e0 = LDB(Wfd, ofW0, 0); e1 = LDB(Wfd, ofW1, 0); e2 = LDB(Wfd, ofW2, 0); e3 = LDB(Wfd, ofW3, 0); }
    step4<7>(acc, hbuf, l15, lhi, o0, o1, o2, o3);
    if (L == 0){ o0 = LDB(WtL1, off0, 1); o1 = LDB(WtL1, off1, 1); o2 = LDB(WtL1, off2, 1); o3 = LDB(WtL1, off3, 1); }
    else       { o0 = LDB(Wfd, ofW0, 1); o1 = LDB(Wfd, ofW1, 1); o2 = LDB(Wfd, ofW2, 1); o3 = LDB(Wfd, ofW3, 1); }

    BAR();   // all waves done READING hbuf before in-place overwrite
    #pragma unroll
    for (int fr = 0; fr < 4; ++fr)
      #pragma unroll
      for (int fc = 0; fc < 4; ++fc)
        #pragma unroll
        for (int j = 0; j < 4; ++j){
          int row = fr * 16 + lhi * 4 + j;
          int col = wave * 64 + fc * 16 + l15;
          float v = lrelu(acc[fr][fc][j] + bias[col]);
          int byte = row * 512 + ((((col >> 3) ^ (row & 7))) << 4) + ((col & 7) << 1);
          *(short*)((char*)&hbuf[0] + byte) = f2bf(v);
        }
    WAITL();  // own epilogue ds_writes drained
    BAR();    // visible to all
  }

  // ---- Wf layer: (64x256)@(256x64) + bf -> tokens overlay in hbuf [m][64]
  // Wave tile 16r x 64c (r0 = wave*16); B in named regs, barrier-free.
  {
    const int r0w = wave * 16;
    f32x4 aw[4];
    #pragma unroll
    for (int fc = 0; fc < 4; ++fc) aw[fc] = (f32x4){0.f, 0.f, 0.f, 0.f};

    stepWf<0>(aw, hbuf, r0w, l15, lhi, e0, e1, e2, e3);
    e0 = LDB(Wfd, ofW0, 2); e1 = LDB(Wfd, ofW1, 2); e2 = LDB(Wfd, ofW2, 2); e3 = LDB(Wfd, ofW3, 2);
    stepWf<1>(aw, hbuf, r0w, l15, lhi, o0, o1, o2, o3);
    o0 = LDB(Wfd, ofW0, 3); o1 = LDB(Wfd, ofW1, 3); o2 = LDB(Wfd, ofW2, 3); o3 = LDB(Wfd, ofW3, 3);
    stepWf<2>(aw, hbuf, r0w, l15, lhi, e0, e1, e2, e3);
    e0 = LDB(Wfd, ofW0, 4); e1 = LDB(Wfd, ofW1, 4); e2 = LDB(Wfd, ofW2, 4); e3 = LDB(Wfd, ofW3, 4);
    stepWf<3>(aw, hbuf, r0w, l15, lhi, o0, o1, o2, o3);
    o0 = LDB(Wfd, ofW0, 5); o1 = LDB(Wfd, ofW1, 5); o2 = LDB(Wfd, ofW2, 5); o3 = LDB(Wfd, ofW3, 5);
    stepWf<4>(aw, hbuf, r0w, l15, lhi, e0, e1, e2, e3);
    e0 = LDB(Wfd, ofW0, 6); e1 = LDB(Wfd, ofW1, 6); e2 = LDB(Wfd, ofW2, 6); e3 = LDB(Wfd, ofW3, 6);
    stepWf<5>(aw, hbuf, r0w, l15, lhi, o0, o1, o2, o3);
    o0 = LDB(Wfd, ofW0, 7); o1 = LDB(Wfd, ofW1, 7); o2 = LDB(Wfd, ofW2, 7); o3 = LDB(Wfd, ofW3, 7);
    stepWf<6>(aw, hbuf, r0w, l15, lhi, e0, e1, e2, e3);
    stepWf<7>(aw, hbuf, r0w, l15, lhi, o0, o1, o2, o3);

    BAR();   // all waves done reading hbuf before token overlay write
    #pragma unroll
    for (int fc = 0; fc < 4; ++fc)
      #pragma unroll
      for (int j = 0; j < 4; ++j){
        int row = r0w + lhi * 4 + j;
        int col = fc * 16 + l15;
        float v = aw[fc][j] + bf_[d * E_N + col];
        int byte = row * 128 + ((((col >> 3) ^ (row & 7))) << 4) + ((col & 7) << 1);
        *(short*)((char*)&hbuf[0] + byte) = f2bf(v);
      }
    WAITL();
    BAR();   // tokens visible to all waves
  }

  // ---- fused QKV: tokens(64x64) @ [Wq|Wk|Wv]^T (64x192); wave = 48-col slice
  // Wqkv is 24KB shared by ALL blocks -> L1/L2-hot; direct global loads fine.
  {
    f32x4 acc[4][3];
    #pragma unroll
    for (int fr = 0; fr < 4; ++fr)
      #pragma unroll
      for (int fc = 0; fc < 3; ++fc) acc[fr][fc] = (f32x4){0.f, 0.f, 0.f, 0.f};
    #pragma unroll
    for (int kk = 0; kk < 2; ++kk){
      bf16x8 af[4];
      #pragma unroll
      for (int fr = 0; fr < 4; ++fr){
        int row = fr * 16 + l15;
        int cch = kk * 4 + lhi;
        af[fr] = *(const bf16x8*)((const char*)&hbuf[0] + row * 128 + ((cch ^ (row & 7)) << 4));
      }
      bf16x8 bqkv[3];
      #pragma unroll
      for (int fc = 0; fc < 3; ++fc){
        int n = wave * 48 + fc * 16 + l15;
        bqkv[fc] = *(const bf16x8*)(Wqkv + (size_t)n * E_N + kk * 32 + lhi * 8);
      }
      #pragma unroll
      for (int fr = 0; fr < 4; ++fr)
        #pragma unroll
        for (int fc = 0; fc < 3; ++fc)
          acc[fr][fc] = __builtin_amdgcn_mfma_f32_16x16x32_bf16(af[fr], bqkv[fc], acc[fr][fc], 0, 0, 0);
    }
    #pragma unroll
    for (int fr = 0; fr < 4; ++fr)
      #pragma unroll
      for (int fc = 0; fc < 3; ++fc)
        #pragma unroll
        for (int j = 0; j < 4; ++j){
          int n = wave * 48 + fc * 16 + l15;
          int g = n >> 6, nl = n & 63;
          float bias = (g == 0) ? bq[nl] : (g == 1 ? bk[nl] : bv[nl]);
          int bg = m0 + fr * 16 + lhi * 4 + j;
          float v = acc[fr][fc][j] + bias;
          qkv[((size_t)bg * D_N + d) * 192 + n] = f2bf(v);
        }
  }
}

// ---------- attention + pool + folded head (R12 passing version, unchanged) ----------
__global__ __launch_bounds__(256, 2) void attn_kernel(
    const short* __restrict__ qkv, const float* __restrict__ wc, float* __restrict__ out)
{
  __shared__ short smem[4][17 * 192];     // per-wave sample tile, XOR-swizzled 16B chunks
  const int tid = threadIdx.x, lane = tid & 63, wave = tid >> 6;
  const int h = lane >> 4, iq = lane & 15;

  const int b = blockIdx.x * 4 + wave;
  const short* src = qkv + (size_t)b * (17 * 192);
  for (int g0 = lane; g0 < 408; g0 += 64){
    int i = g0 / 24, c = g0 % 24;
    bf16x8 v = *(const bf16x8*)(src + g0 * 8);
    *(bf16x8*)((char*)&smem[wave][0] + i * 384 + ((c ^ (i & 7)) << 4)) = v;
  }
  // same-wave LDS RAW is in-order; compiler inserts lgkmcnt waits before uses

  // pre-dot: vtilde_j = v_j . wcomb (head h slice). Lane holds j = iq;
  // j = 16 computed redundantly by every lane (lane-local, no shuffle).
  float vt = 0.f, vt16 = 0.f;
  #pragma unroll
  for (int u2 = 0; u2 < 2; ++u2){
    int cch = 16 + 2 * h + u2;
    bf16x8 vj  = *(const bf16x8*)((char*)&smem[wave][0] + iq * 384 + ((cch ^ (iq & 7)) << 4));
    bf16x8 v16 = *(const bf16x8*)((char*)&smem[wave][0] + 16 * 384 + (cch << 4));
    #pragma unroll
    for (int z = 0; z < 8; ++z){
      float w = wc[h * 16 + u2 * 8 + z];   // transient; L1-broadcast within head group
      vt   += bf2f(vj[z])  * w;
      vt16 += bf2f(v16[z]) * w;
    }
  }

  float part = 0.f;
  #pragma unroll 1
  for (int t = 0; t < 2; ++t){
    const int i = (t == 0) ? iq : 16;    // t=1: ALL lanes compute row 16 (uniform)
    float q[16];
    #pragma unroll
    for (int u2 = 0; u2 < 2; ++u2){
      int cch = 2 * h + u2;
      bf16x8 v = *(const bf16x8*)((char*)&smem[wave][0] + i * 384 + ((cch ^ (i & 7)) << 4));
      #pragma unroll
      for (int z = 0; z < 8; ++z) q[u2 * 8 + z] = bf2f(v[z]);
    }
    // fused softmax-PV: num = sum_j exp(s_j)*vtilde_j ; den = sum_j exp(s_j)
    float num = 0.f, den = 0.f;
    #pragma unroll 1                      // cap in-flight LDS loads / live range
    for (int j = 0; j < 16; ++j){
      float a2 = 0.f;
      #pragma unroll
      for (int u2 = 0; u2 < 2; ++u2){
        int cch = 8 + 2 * h + u2;
        bf16x8 v = *(const bf16x8*)((char*)&smem[wave][0] + j * 384 + ((cch ^ (j & 7)) << 4));
        #pragma unroll
        for (int z = 0; z < 8; ++z) a2 += q[u2 * 8 + z] * bf2f(v[z]);
      }
      float e = __expf(a2 * 0.25f);       // 1/sqrt(16); |s| ~ O(1), exp safe
      num += e * __shfl(vt, (lane & 48) + j);   // uniform: all 64 lanes active
      den += e;
    }
    {  // j = 16 (row swizzle term is 0 since 16&7 == 0)
      float a2 = 0.f;
      #pragma unroll
      for (int u2 = 0; u2 < 2; ++u2){
        int cch = 8 + 2 * h + u2;
        bf16x8 v = *(const bf16x8*)((char*)&smem[wave][0] + 16 * 384 + (cch << 4));
        #pragma unroll
        for (int z = 0; z < 8; ++z) a2 += q[u2 * 8 + z] * bf2f(v[z]);
      }
      float e = __expf(a2 * 0.25f);
      num += e * vt16;
      den += e;
    }
    float contrib = num / den;
    part += (t == 0 || iq == 0) ? contrib : 0.f;     // predicated, not branched
  }
  // out = lrelu( (1/17) * sum part + bcomb ), reduce over 64 lanes (17 i x 4 h)
  #pragma unroll
  for (int off = 1; off < 64; off <<= 1) part += __shfl_xor(part, off);
  if (lane == 0) out[b] = lrelu(part * (1.f / 17.f) + wc[64]);
}

extern "C" void kernel_launch(void* const* d_in, const int* in_sizes, int n_in,
                              void* d_out, int out_size, void* d_ws, size_t ws_size,
                              hipStream_t stream)
{
  const float* x   = (const float*)d_in[0];
  const float* W1  = (const float*)d_in[1];
  const float* b1  = (const float*)d_in[2];
  const float* Wm  = (const float*)d_in[3];
  const float* bm  = (const float*)d_in[4];
  const float* Wf  = (const float*)d_in[5];
  const float* bf_ = (const float*)d_in[6];
  const float* Wq  = (const float*)d_in[7];
  const float* bq  = (const float*)d_in[8];
  const float* Wk  = (const float*)d_in[9];
  const float* bk  = (const float*)d_in[10];
  const float* Wv  = (const float*)d_in[11];
  const float* bv  = (const float*)d_in[12];
  const float* Wo  = (const float*)d_in[13];
  const float* bo  = (const float*)d_in[14];
  const float* Wfc = (const float*)d_in[15];
  const float* bfc = (const float*)d_in[16];
  float* out = (float*)d_out;
  (void)in_sizes; (void)n_in; (void)out_size; (void)ws_size;

  char* ws = (char*)d_ws;
  size_t off = 0;
  auto alloc = [&](size_t bytes) -> char* {
    char* p = ws + off;
    off = (off + bytes + 255) & ~(size_t)255;
    return p;
  };
  short* qkvb  = (short*)alloc((size_t)B_N * D_N * 192 * 2);      // ~102 MB
  short* WmT   = (short*)alloc((size_t)2 * D_N * H_N * H_N * 2);  // 4.5 MB
  short* WfT   = (short*)alloc((size_t)D_N * E_N * H_N * 2);      // 0.56 MB
  short* Wqkvb = (short*)alloc((size_t)192 * E_N * 2);
  float* wcomb = (float*)alloc(65 * sizeof(float));

  transpose_convert<<<dim3(8, 8, 2 * D_N), dim3(32, 8), 0, stream>>>(Wm, WmT, 256, 256);
  transpose_convert<<<dim3(2, 8, D_N),     dim3(32, 8), 0, stream>>>(Wf, WfT, 256, 64);
  convert_wqkv<<<dim3(48), dim3(256), 0, stream>>>(Wq, Wk, Wv, Wqkvb);
  wcomb_kernel<<<dim3(1), dim3(64), 0, stream>>>(Wo, Wfc, bo, bfc, wcomb);

  subnet_kernel<<<dim3(256 * D_N), dim3(256), 0, stream>>>(
      x, W1, b1, bm, bf_, bq, bk, bv, WmT, WfT, Wqkvb, qkvb);

  attn_kernel<<<dim3(4096), dim3(256), 0, stream>>>(qkvb, wcomb, out);
}

// Round 18
// 229.897 us; speedup vs baseline: 1.9555x; 1.2858x over previous
//
#include <hip/hip_runtime.h>
#include <hip/hip_bf16.h>

#define B_N   16384
#define D_N   17
#define H_N   256
#define E_N   64

typedef __attribute__((ext_vector_type(8))) short bf16x8;
typedef __attribute__((ext_vector_type(4))) float f32x4;

#define WAITV(N) asm volatile("s_waitcnt vmcnt(" #N ")" ::: "memory")
#define WAITL()  asm volatile("s_waitcnt lgkmcnt(0)" ::: "memory")
#define BAR()    __builtin_amdgcn_s_barrier()

static __device__ __forceinline__ short f2bf(float f){
  unsigned u = __builtin_bit_cast(unsigned, f);
  unsigned r = (u + 0x7fffu + ((u >> 16) & 1u)) >> 16;   // RNE
  return (short)(unsigned short)r;
}
static __device__ __forceinline__ float bf2f(short s){
  unsigned u = ((unsigned)(unsigned short)s) << 16;
  return __builtin_bit_cast(float, u);
}
static __device__ __forceinline__ float lrelu(float v){ return fmaxf(v, 0.01f * v); }

// async global->LDS, 16B per lane. LDS dest is wave-uniform base + lane*16.
static __device__ __forceinline__ void gload_lds16(const short* g, short* l){
  __builtin_amdgcn_global_load_lds(
      (const __attribute__((address_space(1))) unsigned int*)g,
      (__attribute__((address_space(3))) unsigned int*)l, 16, 0, 0);
}

// ---------- prep: fp32 (G,R,C) -> bf16 (G,C,R) ----------
__global__ void transpose_convert(const float* __restrict__ in, short* __restrict__ outp,
                                  int R, int C){
  __shared__ float tile[32][33];
  int g = blockIdx.z;
  const float* inp = in + (size_t)g * R * C;
  short* op = outp + (size_t)g * R * C;
  int c0 = blockIdx.x * 32, r0 = blockIdx.y * 32;
  for (int i = threadIdx.y; i < 32; i += 8)
    tile[i][threadIdx.x] = inp[(size_t)(r0 + i) * C + c0 + threadIdx.x];
  __syncthreads();
  for (int i = threadIdx.y; i < 32; i += 8)
    op[(size_t)(c0 + i) * R + r0 + threadIdx.x] = f2bf(tile[threadIdx.x][i]);
}

// ---------- prep: stack+convert Wq|Wk|Wv -> bf16 [192][64] ----------
__global__ void convert_wqkv(const float* __restrict__ Wq, const float* __restrict__ Wk,
                             const float* __restrict__ Wv, short* __restrict__ outw){
  int i = blockIdx.x * 256 + threadIdx.x;        // 0..12287
  int g = i >> 12, r = i & 4095;
  const float* W = (g == 0) ? Wq : (g == 1 ? Wk : Wv);
  outw[i] = f2bf(W[r]);
}

// ---------- prep: wcomb[e] = sum_eo Wo[eo][e]*Wfc[eo]; wcomb[64] = bo.Wfc + bfc ----------
__global__ void wcomb_kernel(const float* __restrict__ Wo, const float* __restrict__ Wfc,
                             const float* __restrict__ bo, const float* __restrict__ bfc,
                             float* __restrict__ wcomb){
  int e = threadIdx.x;
  float acc = 0.f;
  for (int eo = 0; eo < 64; ++eo) acc += Wo[eo * 64 + e] * Wfc[eo];
  wcomb[e] = acc;
  if (e == 0){
    float bc = bfc[0];
    for (int eo = 0; eo < 64; ++eo) bc += bo[eo] * Wfc[eo];
    wcomb[64] = bc;
  }
}

// Middle-layer slice staging (512-thr block). Slice kk of [256][256] bf16 =
// 16 KB = 1024 x 16B chunks, 2/thread (2 vmcnt instr per wave). Chunk swizzle
// on the GLOBAL source (gload_lds writes linearly); read XORs the same term.
static __device__ __forceinline__ void stage_w256(const short* Wt, int kk, short* wb,
                                                  int tid, int wave){
  #pragma unroll
  for (int r = 0; r < 2; ++r){
    int li = r * 512 + tid;
    int n  = li >> 2;
    int cc = (li & 3) ^ ((n >> 1) & 3);
    gload_lds16(Wt + n * 256 + kk * 32 + cc * 8,
                wb + (size_t)(r * 512 + wave * 64) * 8);
  }
}
// Wf PAIR staging: slices kk0,kk0+1 (2 x 4 KB) in one call, 1 instr/wave
// (keeps the per-wave vmcnt ledger uniform). sub = tid>>8 is wave-uniform.
static __device__ __forceinline__ void stage_wf_pair(const short* Wfd, int kk0, short* wb,
                                                     int tid, int wave){
  int sub = tid >> 8;
  int u   = tid & 255;
  int n   = u >> 2;
  int cc  = (u & 3) ^ ((n >> 1) & 3);
  gload_lds16(Wfd + n * 256 + (kk0 + sub) * 32 + cc * 8,
              wb + sub * 2048 + (size_t)((wave & 3) * 64) * 8);
}

// ---------- main subnet kernel (R14 config: session-best 230.5us total) ----------
// Landscape after 17 rounds: every spill-free variant lands 187-255us subnet
// (MfmaUtil ~20%, HBM ~10%) — latency-bound, occupancy capped by the unified
// VGPR+AGPR file. R14 = best: wave tile 32x64 (acc[2][4]=32 AGPR), 8 waves on
// one 64-sample tile, 4 waves/SIMD + 2 independent blocks/CU (80KB LDS),
// tri-buffered staged weights with counted vmcnt (never 0 in the loop).
// Known mild spill (+55MB WRITE) at the (512,4)=128 cap — measured faster
// than every clean alternative (R12 195 / R13 197 / R17 255 vs this 187).
__global__ __launch_bounds__(512, 4) void subnet_kernel(
    const float* __restrict__ x, const float* __restrict__ W1, const float* __restrict__ b1,
    const float* __restrict__ bm, const float* __restrict__ bf_,
    const float* __restrict__ bq, const float* __restrict__ bk, const float* __restrict__ bv,
    const short* __restrict__ WmT, const short* __restrict__ WfT, const short* __restrict__ Wqkv,
    short* __restrict__ qkv)
{
  __shared__ short hbuf[64 * 256];       // 32 KB activations (tokens overlay head)
  __shared__ short wbuf[3][256 * 32];    // 3 x 16 KB weight slices

  // XCD swizzle: 4352 = 8*544, d-major (per-XCD weight set L2-resident)
  int wg = blockIdx.x;
  int idx = (wg & 7) * 544 + (wg >> 3);
  const int d  = idx >> 8;
  const int m0 = (idx & 255) * 64;

  const int tid = threadIdx.x;
  const int lane = tid & 63, wave = tid >> 6;
  const int wr = wave >> 2, wv = wave & 3;     // row-half, 64-col slice
  const int l15 = lane & 15, lhi = lane >> 4;

  const short* WtL0 = WmT + (size_t)(0 * D_N + d) * (H_N * H_N);
  const short* WtL1 = WmT + (size_t)(1 * D_N + d) * (H_N * H_N);
  const short* Wfd  = WfT + (size_t)d * (E_N * H_N);

  // prologue: slices 0,1 fly during phase 0 (4 outstanding/wave)
  stage_w256(WtL0, 0, &wbuf[0][0], tid, wave);
  stage_w256(WtL0, 1, &wbuf[1][0], tid, wave);

  // ---- phase 0: h0 = lrelu(x*W1+b1) -> swizzled LDS [m][k], packed b32 writes
  {
    const int kp = tid & 127;            // k-pair, k0 = 2*kp
    const int mq = tid >> 7;             // 0..3 -> 16-row group
    const float w1a = W1[d * H_N + 2 * kp], w1b = W1[d * H_N + 2 * kp + 1];
    const float b1a = b1[d * H_N + 2 * kp], b1b = b1[d * H_N + 2 * kp + 1];
    #pragma unroll
    for (int i = 0; i < 16; ++i){
      int m = mq * 16 + i;
      float xv = x[(size_t)(m0 + m) * D_N + d];
      unsigned lo = (unsigned short)f2bf(lrelu(xv * w1a + b1a));
      unsigned hi = (unsigned short)f2bf(lrelu(xv * w1b + b1b));
      int byte = m * 512 + ((((kp >> 2) ^ (m & 7))) << 4) + ((kp & 3) << 2);
      *(unsigned*)((char*)&hbuf[0] + byte) = lo | (hi << 16);
    }
  }
  WAITL();   // drain own h0 ds_writes; visibility via first step barrier

  // ---- 2 middle layers: (64x256)@(256x256); wave tile 32r x 64c; in-place
  for (int L = 0; L < 2; ++L){
    const float* bias = bm + (size_t)(L * D_N + d) * H_N;
    f32x4 acc[2][4];
    #pragma unroll
    for (int a = 0; a < 2; ++a)
      #pragma unroll
      for (int c = 0; c < 4; ++c) acc[a][c] = (f32x4){0.f, 0.f, 0.f, 0.f};

    for (int kk = 0; kk < 8; ++kk){
      const int s = L * 8 + kk;
      // ledger: outstanding 4 normally (slices s, s+1; 2 instr each);
      // at s=15: s15(2)+w0(1)=3 -> WAITV(1) leaves w0 in flight.
      if (s == 15) { WAITV(1); } else { WAITV(2); }
      BAR();
      const int s2 = s + 2;
      if (s2 < 8)       stage_w256(WtL0, s2,              &wbuf[s2 % 3][0], tid, wave);
      else if (s2 < 16) stage_w256(WtL1, s2 - 8,          &wbuf[s2 % 3][0], tid, wave);
      else              stage_wf_pair(Wfd, (s2 - 16) * 2, &wbuf[s2 % 3][0], tid, wave);

      const short* wb = &wbuf[s % 3][0];
      bf16x8 af[2], bfr[4];
      #pragma unroll
      for (int fr = 0; fr < 2; ++fr){
        int row = wr * 32 + fr * 16 + l15;
        int cch = kk * 4 + lhi;
        af[fr] = *(const bf16x8*)((const char*)&hbuf[0] + row * 512 + ((cch ^ (row & 7)) << 4));
      }
      #pragma unroll
      for (int fc = 0; fc < 4; ++fc){
        int n = wv * 64 + fc * 16 + l15;
        bfr[fc] = *(const bf16x8*)((const char*)wb + n * 64 + ((lhi ^ ((n >> 1) & 3)) << 4));
      }
      #pragma unroll
      for (int fr = 0; fr < 2; ++fr)
        #pragma unroll
        for (int fc = 0; fc < 4; ++fc)
          acc[fr][fc] = __builtin_amdgcn_mfma_f32_16x16x32_bf16(af[fr], bfr[fc], acc[fr][fc], 0, 0, 0);
    }
    BAR();   // all waves done reading hbuf before in-place overwrite
    #pragma unroll
    for (int fr = 0; fr < 2; ++fr)
      #pragma unroll
      for (int fc = 0; fc < 4; ++fc)
        #pragma unroll
        for (int j = 0; j < 4; ++j){
          int row = wr * 32 + fr * 16 + lhi * 4 + j;
          int col = wv * 64 + fc * 16 + l15;
          float v = lrelu(acc[fr][fc][j] + bias[col]);
          int byte = row * 512 + ((((col >> 3) ^ (row & 7))) << 4) + ((col & 7) << 1);
          *(short*)((char*)&hbuf[0] + byte) = f2bf(v);
        }
    WAITL();  // drain own epilogue ds_writes; visibility via next step barrier
  }

  // ---- Wf layer: (64x256)@(256x64) + bf -> tokens overlay in hbuf [m][64]
  // 4 steps, 2 k-slices each (Wf pairs w0..w3 at stream 16..19).
  // Wave tile 16r x 32c: r0 = (wave>>1)*16, c0 = (wave&1)*32, acc[2].
  {
    const int r0 = (wave >> 1) * 16, c0 = (wave & 1) * 32;
    f32x4 acc[2];
    acc[0] = (f32x4){0.f, 0.f, 0.f, 0.f};
    acc[1] = (f32x4){0.f, 0.f, 0.f, 0.f};
    for (int t = 0; t < 4; ++t){
      if (t == 3) { WAITV(0); } else { WAITV(1); }
      BAR();
      if (t < 2) stage_wf_pair(Wfd, (t + 2) * 2, &wbuf[(18 + t) % 3][0], tid, wave);
      const short* wbase = &wbuf[(16 + t) % 3][0];
      #pragma unroll
      for (int kkh = 0; kkh < 2; ++kkh){
        int kk = 2 * t + kkh;
        int row = r0 + l15;
        int cch = kk * 4 + lhi;
        bf16x8 a = *(const bf16x8*)((const char*)&hbuf[0] + row * 512 + ((cch ^ (row & 7)) << 4));
        const short* wbs = wbase + kkh * 2048;
        #pragma unroll
        for (int fc = 0; fc < 2; ++fc){
          int n = c0 + fc * 16 + l15;
          bf16x8 b = *(const bf16x8*)((const char*)wbs + n * 64 + ((lhi ^ ((n >> 1) & 3)) << 4));
          acc[fc] = __builtin_amdgcn_mfma_f32_16x16x32_bf16(a, b, acc[fc], 0, 0, 0);
        }
      }
    }
    BAR();   // all waves done reading hbuf activations before token overlay write
    #pragma unroll
    for (int fc = 0; fc < 2; ++fc)
      #pragma unroll
      for (int j = 0; j < 4; ++j){
        int row = r0 + lhi * 4 + j;
        int col = c0 + fc * 16 + l15;
        float v = acc[fc][j] + bf_[d * E_N + col];
        int byte = row * 128 + ((((col >> 3) ^ (row & 7))) << 4) + ((col & 7) << 1);
        *(short*)((char*)&hbuf[0] + byte) = f2bf(v);
      }
    WAITL();
    BAR();   // tokens visible to all waves
  }

  // ---- fused QKV: tokens(64x64) @ [Wq|Wk|Wv]^T (64x192); wave tile 16r x 96c
  // Wqkv is 24KB shared by ALL blocks -> L1/L2-hot; direct global loads fine.
  {
    const int r0 = (wave & 3) * 16, c0 = (wave >> 2) * 96;
    f32x4 acc[6];
    #pragma unroll
    for (int fc = 0; fc < 6; ++fc) acc[fc] = (f32x4){0.f, 0.f, 0.f, 0.f};
    #pragma unroll
    for (int kk = 0; kk < 2; ++kk){
      int row = r0 + l15;
      int cch = kk * 4 + lhi;
      bf16x8 a = *(const bf16x8*)((const char*)&hbuf[0] + row * 128 + ((cch ^ (row & 7)) << 4));
      #pragma unroll
      for (int fc = 0; fc < 6; ++fc){
        int n = c0 + fc * 16 + l15;
        bf16x8 b = *(const bf16x8*)(Wqkv + (size_t)n * E_N + kk * 32 + lhi * 8);
        acc[fc] = __builtin_amdgcn_mfma_f32_16x16x32_bf16(a, b, acc[fc], 0, 0, 0);
      }
    }
    #pragma unroll
    for (int fc = 0; fc < 6; ++fc)
      #pragma unroll
      for (int j = 0; j < 4; ++j){
        int n = c0 + fc * 16 + l15;
        int g = n >> 6, nl = n & 63;
        float bias = (g == 0) ? bq[nl] : (g == 1 ? bk[nl] : bv[nl]);
        int bg = m0 + r0 + lhi * 4 + j;
        float v = acc[fc][j] + bias;
        qkv[((size_t)bg * D_N + d) * 192 + n] = f2bf(v);
      }
  }
}

// ---------- attention + pool + folded head (R12 passing version, unchanged) ----------
__global__ __launch_bounds__(256, 2) void attn_kernel(
    const short* __restrict__ qkv, const float* __restrict__ wc, float* __restrict__ out)
{
  __shared__ short smem[4][17 * 192];     // per-wave sample tile, XOR-swizzled 16B chunks
  const int tid = threadIdx.x, lane = tid & 63, wave = tid >> 6;
  const int h = lane >> 4, iq = lane & 15;

  const int b = blockIdx.x * 4 + wave;
  const short* src = qkv + (size_t)b * (17 * 192);
  for (int g0 = lane; g0 < 408; g0 += 64){
    int i = g0 / 24, c = g0 % 24;
    bf16x8 v = *(const bf16x8*)(src + g0 * 8);
    *(bf16x8*)((char*)&smem[wave][0] + i * 384 + ((c ^ (i & 7)) << 4)) = v;
  }
  // same-wave LDS RAW is in-order; compiler inserts lgkmcnt waits before uses

  // pre-dot: vtilde_j = v_j . wcomb (head h slice). Lane holds j = iq;
  // j = 16 computed redundantly by every lane (lane-local, no shuffle).
  float vt = 0.f, vt16 = 0.f;
  #pragma unroll
  for (int u2 = 0; u2 < 2; ++u2){
    int cch = 16 + 2 * h + u2;
    bf16x8 vj  = *(const bf16x8*)((char*)&smem[wave][0] + iq * 384 + ((cch ^ (iq & 7)) << 4));
    bf16x8 v16 = *(const bf16x8*)((char*)&smem[wave][0] + 16 * 384 + (cch << 4));
    #pragma unroll
    for (int z = 0; z < 8; ++z){
      float w = wc[h * 16 + u2 * 8 + z];   // transient; L1-broadcast within head group
      vt   += bf2f(vj[z])  * w;
      vt16 += bf2f(v16[z]) * w;
    }
  }

  float part = 0.f;
  #pragma unroll 1
  for (int t = 0; t < 2; ++t){
    const int i = (t == 0) ? iq : 16;    // t=1: ALL lanes compute row 16 (uniform)
    float q[16];
    #pragma unroll
    for (int u2 = 0; u2 < 2; ++u2){
      int cch = 2 * h + u2;
      bf16x8 v = *(const bf16x8*)((char*)&smem[wave][0] + i * 384 + ((cch ^ (i & 7)) << 4));
      #pragma unroll
      for (int z = 0; z < 8; ++z) q[u2 * 8 + z] = bf2f(v[z]);
    }
    // fused softmax-PV: num = sum_j exp(s_j)*vtilde_j ; den = sum_j exp(s_j)
    float num = 0.f, den = 0.f;
    #pragma unroll 1                      // cap in-flight LDS loads / live range
    for (int j = 0; j < 16; ++j){
      float a2 = 0.f;
      #pragma unroll
      for (int u2 = 0; u2 < 2; ++u2){
        int cch = 8 + 2 * h + u2;
        bf16x8 v = *(const bf16x8*)((char*)&smem[wave][0] + j * 384 + ((cch ^ (j & 7)) << 4));
        #pragma unroll
        for (int z = 0; z < 8; ++z) a2 += q[u2 * 8 + z] * bf2f(v[z]);
      }
      float e = __expf(a2 * 0.25f);       // 1/sqrt(16); |s| ~ O(1), exp safe
      num += e * __shfl(vt, (lane & 48) + j);   // uniform: all 64 lanes active
      den += e;
    }
    {  // j = 16 (row swizzle term is 0 since 16&7 == 0)
      float a2 = 0.f;
      #pragma unroll
      for (int u2 = 0; u2 < 2; ++u2){
        int cch = 8 + 2 * h + u2;
        bf16x8 v = *(const bf16x8*)((char*)&smem[wave][0] + 16 * 384 + (cch << 4));
        #pragma unroll
        for (int z = 0; z < 8; ++z) a2 += q[u2 * 8 + z] * bf2f(v[z]);
      }
      float e = __expf(a2 * 0.25f);
      num += e * vt16;
      den += e;
    }
    float contrib = num / den;
    part += (t == 0 || iq == 0) ? contrib : 0.f;     // predicated, not branched
  }
  // out = lrelu( (1/17) * sum part + bcomb ), reduce over 64 lanes (17 i x 4 h)
  #pragma unroll
  for (int off = 1; off < 64; off <<= 1) part += __shfl_xor(part, off);
  if (lane == 0) out[b] = lrelu(part * (1.f / 17.f) + wc[64]);
}

extern "C" void kernel_launch(void* const* d_in, const int* in_sizes, int n_in,
                              void* d_out, int out_size, void* d_ws, size_t ws_size,
                              hipStream_t stream)
{
  const float* x   = (const float*)d_in[0];
  const float* W1  = (const float*)d_in[1];
  const float* b1  = (const float*)d_in[2];
  const float* Wm  = (const float*)d_in[3];
  const float* bm  = (const float*)d_in[4];
  const float* Wf  = (const float*)d_in[5];
  const float* bf_ = (const float*)d_in[6];
  const float* Wq  = (const float*)d_in[7];
  const float* bq  = (const float*)d_in[8];
  const float* Wk  = (const float*)d_in[9];
  const float* bk  = (const float*)d_in[10];
  const float* Wv  = (const float*)d_in[11];
  const float* bv  = (const float*)d_in[12];
  const float* Wo  = (const float*)d_in[13];
  const float* bo  = (const float*)d_in[14];
  const float* Wfc = (const float*)d_in[15];
  const float* bfc = (const float*)d_in[16];
  float* out = (float*)d_out;
  (void)in_sizes; (void)n_in; (void)out_size; (void)ws_size;

  char* ws = (char*)d_ws;
  size_t off = 0;
  auto alloc = [&](size_t bytes) -> char* {
    char* p = ws + off;
    off = (off + bytes + 255) & ~(size_t)255;
    return p;
  };
  short* qkvb  = (short*)alloc((size_t)B_N * D_N * 192 * 2);      // ~102 MB
  short* WmT   = (short*)alloc((size_t)2 * D_N * H_N * H_N * 2);  // 4.5 MB
  short* WfT   = (short*)alloc((size_t)D_N * E_N * H_N * 2);      // 0.56 MB
  short* Wqkvb = (short*)alloc((size_t)192 * E_N * 2);
  float* wcomb = (float*)alloc(65 * sizeof(float));

  transpose_convert<<<dim3(8, 8, 2 * D_N), dim3(32, 8), 0, stream>>>(Wm, WmT, 256, 256);
  transpose_convert<<<dim3(2, 8, D_N),     dim3(32, 8), 0, stream>>>(Wf, WfT, 256, 64);
  convert_wqkv<<<dim3(48), dim3(256), 0, stream>>>(Wq, Wk, Wv, Wqkvb);
  wcomb_kernel<<<dim3(1), dim3(64), 0, stream>>>(Wo, Wfc, bo, bfc, wcomb);

  subnet_kernel<<<dim3(256 * D_N), dim3(512), 0, stream>>>(
      x, W1, b1, bm, bf_, bq, bk, bv, WmT, WfT, Wqkvb, qkvb);

  attn_kernel<<<dim3(4096), dim3(256), 0, stream>>>(qkvb, wcomb, out);
}